// Round 1
// baseline (434.187 us; speedup 1.0000x reference)
//
#include <hip/hip_runtime.h>
#include <hip/hip_bf16.h>

typedef __bf16 bf16x8 __attribute__((ext_vector_type(8)));
typedef float  f32x4  __attribute__((ext_vector_type(4)));
typedef unsigned short u16;

// ---------- helpers ----------
static __device__ __forceinline__ u16 f2bf(float f) {
  union { float f; unsigned u; } v; v.f = f;
  unsigned r = v.u + 0x7fffu + ((v.u >> 16) & 1u);   // RNE
  return (u16)(r >> 16);
}

static __device__ __forceinline__ void gld16(const void* g, void* l) {
  __builtin_amdgcn_global_load_lds(
      (const __attribute__((address_space(1))) unsigned int*)g,
      (__attribute__((address_space(3))) unsigned int*)l, 16, 0, 0);
}

// ---------- weight transpose + cast: W[K,N] f32 -> Wt[N,K] bf16 ----------
__global__ __launch_bounds__(256) void transpose_cast_k(
    const float* __restrict__ W, u16* __restrict__ Wt, int K, int N) {
  __shared__ float tile[32][33];
  const int t = threadIdx.x;
  const int n0 = blockIdx.x * 32, k0 = blockIdx.y * 32;
  const int r = t >> 3, c4 = (t & 7) * 4;
  const float4 v = *(const float4*)(W + (size_t)(k0 + r) * N + n0 + c4);
  tile[r][c4 + 0] = v.x; tile[r][c4 + 1] = v.y;
  tile[r][c4 + 2] = v.z; tile[r][c4 + 3] = v.w;
  __syncthreads();
  const int n = t >> 3, k4 = (t & 7) * 4;
  uint2 pk;
  pk.x = f2bf(tile[k4 + 0][n]) | ((unsigned)f2bf(tile[k4 + 1][n]) << 16);
  pk.y = f2bf(tile[k4 + 2][n]) | ((unsigned)f2bf(tile[k4 + 3][n]) << 16);
  *(uint2*)(Wt + (size_t)(n0 + n) * K + k0 + k4) = pk;
}

// ---------- layernorm f32 -> bf16 (row = 1024) ----------
__global__ __launch_bounds__(256) void ln_cast_k(
    const float* __restrict__ x, const float* __restrict__ g,
    const float* __restrict__ b, u16* __restrict__ out) {
  __shared__ float red[2][4];
  const int t = threadIdx.x;
  const size_t row = blockIdx.x;
  const float4 v = *(const float4*)(x + row * 1024 + t * 4);
  float s = v.x + v.y + v.z + v.w;
  float ss = v.x * v.x + v.y * v.y + v.z * v.z + v.w * v.w;
  #pragma unroll
  for (int m = 1; m <= 32; m <<= 1) { s += __shfl_xor(s, m); ss += __shfl_xor(ss, m); }
  if ((t & 63) == 0) { red[0][t >> 6] = s; red[1][t >> 6] = ss; }
  __syncthreads();
  s  = red[0][0] + red[0][1] + red[0][2] + red[0][3];
  ss = red[1][0] + red[1][1] + red[1][2] + red[1][3];
  const float mu = s * (1.f / 1024.f);
  const float var = ss * (1.f / 1024.f) - mu * mu;
  const float rs = rsqrtf(var + 1e-5f);
  const float4 gv = *(const float4*)(g + t * 4);
  const float4 bv = *(const float4*)(b + t * 4);
  uint2 pk;
  pk.x = f2bf((v.x - mu) * rs * gv.x + bv.x) |
         ((unsigned)f2bf((v.y - mu) * rs * gv.y + bv.y) << 16);
  pk.y = f2bf((v.z - mu) * rs * gv.z + bv.z) |
         ((unsigned)f2bf((v.w - mu) * rs * gv.w + bv.w) << 16);
  *(uint2*)(out + row * 1024 + t * 4) = pk;
}

// ---------- GEMM: C[M,N] = A[M,K](bf16) @ Bt[N,K](bf16)^T + bias, epilogues ----------
// EPI: 0 = store bf16; 1 = exact GELU -> bf16; 2 = +resid -> f32; 3 = qkv (bf16 + V^T copy)
template <int EPI>
__global__ __launch_bounds__(256, 2) void gemm_bt_k(
    const u16* __restrict__ A, const u16* __restrict__ Bt,
    const float* __restrict__ bias, u16* __restrict__ Cb, float* __restrict__ Cf,
    const float* __restrict__ R, u16* __restrict__ vT, int M, int N, int K) {
  __shared__ u16 lA[128 * 64];
  __shared__ u16 lB[128 * 64];
  const int t = threadIdx.x;
  const int mt = M >> 7;
  const int tm = blockIdx.x % mt, tn = blockIdx.x / mt;
  const int lo = t & 15, hi = (t >> 4) & 3, wid = t >> 6;
  const int wm = wid >> 1, wn = wid & 1;
  const int srow = t >> 3, scol = (t & 7) * 8;
  const u16* ga = A + (size_t)(tm * 128 + srow) * K + scol;
  const u16* gb = Bt + (size_t)(tn * 128 + srow) * K + scol;
  f32x4 acc[4][4];
  #pragma unroll
  for (int i = 0; i < 4; ++i)
    #pragma unroll
    for (int j = 0; j < 4; ++j) acc[i][j] = (f32x4){0.f, 0.f, 0.f, 0.f};

  for (int k0 = 0; k0 < K; k0 += 64) {
    #pragma unroll
    for (int j = 0; j < 4; ++j) {
      gld16(ga + (size_t)32 * j * K + k0, &lA[(j * 256 + t) * 8]);
      gld16(gb + (size_t)32 * j * K + k0, &lB[(j * 256 + t) * 8]);
    }
    __syncthreads();
    #pragma unroll
    for (int kk = 0; kk < 2; ++kk) {
      bf16x8 af[4], bf[4];
      #pragma unroll
      for (int mi = 0; mi < 4; ++mi)
        af[mi] = *(const bf16x8*)&lA[(wm * 64 + mi * 16 + lo) * 64 + kk * 32 + hi * 8];
      #pragma unroll
      for (int ni = 0; ni < 4; ++ni)
        bf[ni] = *(const bf16x8*)&lB[(wn * 64 + ni * 16 + lo) * 64 + kk * 32 + hi * 8];
      #pragma unroll
      for (int mi = 0; mi < 4; ++mi)
        #pragma unroll
        for (int ni = 0; ni < 4; ++ni)
          acc[mi][ni] = __builtin_amdgcn_mfma_f32_16x16x32_bf16(af[mi], bf[ni], acc[mi][ni], 0, 0, 0);
    }
    __syncthreads();
  }

  #pragma unroll
  for (int ni = 0; ni < 4; ++ni) {
    const int col = tn * 128 + wn * 64 + ni * 16 + lo;
    const float bv = bias[col];
    #pragma unroll
    for (int mi = 0; mi < 4; ++mi) {
      const int row0 = tm * 128 + wm * 64 + mi * 16 + hi * 4;
      const f32x4 v = acc[mi][ni];
      float vals[4];
      #pragma unroll
      for (int r = 0; r < 4; ++r) {
        float val = v[r] + bv;
        if (EPI == 1) val = 0.5f * val * (1.f + erff(val * 0.70710678118f));
        vals[r] = val;
      }
      if (EPI == 2) {
        #pragma unroll
        for (int r = 0; r < 4; ++r) {
          const size_t idx = (size_t)(row0 + r) * N + col;
          Cf[idx] = vals[r] + R[idx];
        }
      } else {
        #pragma unroll
        for (int r = 0; r < 4; ++r)
          Cb[(size_t)(row0 + r) * N + col] = f2bf(vals[r]);
        if (EPI == 3 && col >= 2048) {
          const int bb = row0 >> 10, n = row0 & 1023;
          const int hh = (col - 2048) >> 6, d = col & 63;
          uint2 pk;
          pk.x = f2bf(vals[0]) | ((unsigned)f2bf(vals[1]) << 16);
          pk.y = f2bf(vals[2]) | ((unsigned)f2bf(vals[3]) << 16);
          *(uint2*)(vT + ((size_t)((bb * 16 + hh) * 64 + d) << 10) + n) = pk;
        }
      }
    }
  }
}

// ---------- flash attention: S^T = K@Q^T (swapped), online softmax, O = P@V ----------
// qkv: [8192][3072] bf16 (Q|K|V per head), vT: [b][h][d][n] bf16, o: [8192][1024] bf16
__global__ __launch_bounds__(256, 2) void attn_k(
    const u16* __restrict__ qkv, const u16* __restrict__ vT, u16* __restrict__ o) {
  __shared__ u16 lK[64 * 64];
  __shared__ u16 lV[64 * 64];   // V^T tile: [d=64][kv=64]
  __shared__ u16 lP[64 * 72];   // P tile: [q=64][kv=64] (+pad)
  const int t = threadIdx.x;
  const int lo = t & 15, hi = (t >> 4) & 3, w = t >> 6;
  const int qt = blockIdx.x & 15, bh = blockIdx.x >> 4;
  const int b = bh >> 4, h = bh & 15;
  const int q0 = qt * 64;
  const u16* Qb = qkv + (size_t)b * 1024 * 3072 + h * 64;
  const u16* Kb = Qb + 1024;
  const u16* Vt = vT + (size_t)bh * 64 * 1024;

  bf16x8 qf[2];
  {
    const size_t q = q0 + w * 16 + lo;
    qf[0] = *(const bf16x8*)(Qb + q * 3072 + hi * 8);
    qf[1] = *(const bf16x8*)(Qb + q * 3072 + 32 + hi * 8);
  }
  f32x4 oacc[4];
  #pragma unroll
  for (int i = 0; i < 4; ++i) oacc[i] = (f32x4){0.f, 0.f, 0.f, 0.f};
  float m = -1e30f, lsum = 0.f;
  const int srow = t >> 3, scol = (t & 7) * 8;

  for (int kv0 = 0; kv0 < 1024; kv0 += 64) {
    __syncthreads();
    #pragma unroll
    for (int j = 0; j < 2; ++j) {
      const int row = j * 32 + srow;
      gld16(Kb + (size_t)(kv0 + row) * 3072 + scol, &lK[(j * 256 + t) * 8]);
      gld16(Vt + (size_t)row * 1024 + kv0 + scol, &lV[(j * 256 + t) * 8]);
    }
    __syncthreads();

    f32x4 s[4];
    #pragma unroll
    for (int i = 0; i < 4; ++i) s[i] = (f32x4){0.f, 0.f, 0.f, 0.f};
    #pragma unroll
    for (int kk = 0; kk < 2; ++kk) {
      #pragma unroll
      for (int mi = 0; mi < 4; ++mi) {
        const bf16x8 kf = *(const bf16x8*)&lK[(mi * 16 + lo) * 64 + kk * 32 + hi * 8];
        s[mi] = __builtin_amdgcn_mfma_f32_16x16x32_bf16(kf, qf[kk], s[mi], 0, 0, 0);
      }
    }
    // softmax over kv for q = q0 + w*16 + lo (lane-local 16 values + hi-group reduce)
    float sv[16];
    float tmax = -1e30f;
    #pragma unroll
    for (int mi = 0; mi < 4; ++mi)
      #pragma unroll
      for (int r = 0; r < 4; ++r) {
        const float xx = s[mi][r] * 0.125f;
        sv[mi * 4 + r] = xx;
        tmax = fmaxf(tmax, xx);
      }
    tmax = fmaxf(tmax, __shfl_xor(tmax, 16));
    tmax = fmaxf(tmax, __shfl_xor(tmax, 32));
    const float mnew = fmaxf(m, tmax);
    const float alpha = __expf(m - mnew);
    m = mnew;
    float p[16], ts = 0.f;
    #pragma unroll
    for (int i = 0; i < 16; ++i) { p[i] = __expf(sv[i] - mnew); ts += p[i]; }
    ts += __shfl_xor(ts, 16);
    ts += __shfl_xor(ts, 32);
    lsum = lsum * alpha + ts;
    // write P^T fragments -> lP[q][kv]; regs r are kv-consecutive -> b64 writes
    #pragma unroll
    for (int mi = 0; mi < 4; ++mi) {
      uint2 pk;
      pk.x = f2bf(p[mi * 4 + 0]) | ((unsigned)f2bf(p[mi * 4 + 1]) << 16);
      pk.y = f2bf(p[mi * 4 + 2]) | ((unsigned)f2bf(p[mi * 4 + 3]) << 16);
      *(uint2*)&lP[(w * 16 + lo) * 72 + mi * 16 + hi * 4] = pk;
    }
    asm volatile("s_waitcnt lgkmcnt(0)" ::: "memory");  // per-wave private rows; RAW fence
    // rescale O by exp(m_old - m_new), redistributed to acc row layout
    float ar[4];
    #pragma unroll
    for (int r = 0; r < 4; ++r) ar[r] = __shfl(alpha, hi * 4 + r);
    #pragma unroll
    for (int ni = 0; ni < 4; ++ni)
      #pragma unroll
      for (int r = 0; r < 4; ++r) oacc[ni][r] *= ar[r];
    // O += P @ V
    #pragma unroll
    for (int kk = 0; kk < 2; ++kk) {
      const bf16x8 pf = *(const bf16x8*)&lP[(w * 16 + lo) * 72 + kk * 32 + hi * 8];
      #pragma unroll
      for (int ni = 0; ni < 4; ++ni) {
        const bf16x8 vf = *(const bf16x8*)&lV[(ni * 16 + lo) * 64 + kk * 32 + hi * 8];
        oacc[ni] = __builtin_amdgcn_mfma_f32_16x16x32_bf16(pf, vf, oacc[ni], 0, 0, 0);
      }
    }
  }
  float lr[4];
  #pragma unroll
  for (int r = 0; r < 4; ++r) lr[r] = 1.f / __shfl(lsum, hi * 4 + r);
  #pragma unroll
  for (int ni = 0; ni < 4; ++ni) {
    const int d = ni * 16 + lo;
    #pragma unroll
    for (int r = 0; r < 4; ++r) {
      const int n = q0 + w * 16 + hi * 4 + r;
      o[((size_t)(b * 1024 + n) * 16 + h) * 64 + d] = f2bf(oacc[ni][r] * lr[r]);
    }
  }
}

// ---------- launch ----------
extern "C" void kernel_launch(void* const* d_in, const int* in_sizes, int n_in,
                              void* d_out, int out_size, void* d_ws, size_t ws_size,
                              hipStream_t stream) {
  const float* x      = (const float*)d_in[0];
  const float* qkv_w  = (const float*)d_in[1];
  const float* qkv_b  = (const float*)d_in[2];
  const float* proj_w = (const float*)d_in[3];
  const float* proj_b = (const float*)d_in[4];
  const float* fc1_w  = (const float*)d_in[5];
  const float* fc1_b  = (const float*)d_in[6];
  const float* fc2_w  = (const float*)d_in[7];
  const float* fc2_b  = (const float*)d_in[8];
  const float* ln1_g  = (const float*)d_in[9];
  const float* ln1_b  = (const float*)d_in[10];
  const float* ln2_g  = (const float*)d_in[11];
  const float* ln2_b  = (const float*)d_in[12];
  float* out = (float*)d_out;
  char* ws = (char*)d_ws;
  // ws layout (bytes); total = 109,051,904 (~104 MB)
  u16* wqkvT = (u16*)(ws);              // [3072][1024]  6,291,456
  u16* wprojT = (u16*)(ws + 6291456);   // [1024][1024]  2,097,152
  u16* wfc1T = (u16*)(ws + 8388608);    // [4096][1024]  8,388,608
  u16* wfc2T = (u16*)(ws + 16777216);   // [1024][4096]  8,388,608
  u16* hbuf  = (u16*)(ws + 25165824);   // [8192][1024] 16,777,216  (h / o / h2 time-shared)
  u16* qkvo  = (u16*)(ws + 41943040);   // [8192][3072] 50,331,648
  u16* vT    = (u16*)(ws + 92274688);   // [128][64][1024] 16,777,216
  u16* fc1o  = qkvo;                    // [8192][4096] 67,108,864 (overlays qkv+vT, both dead)

  transpose_cast_k<<<dim3(96, 32),  256, 0, stream>>>(qkv_w,  wqkvT, 1024, 3072);
  transpose_cast_k<<<dim3(32, 32),  256, 0, stream>>>(proj_w, wprojT, 1024, 1024);
  transpose_cast_k<<<dim3(128, 32), 256, 0, stream>>>(fc1_w,  wfc1T, 1024, 4096);
  transpose_cast_k<<<dim3(32, 128), 256, 0, stream>>>(fc2_w,  wfc2T, 4096, 1024);
  ln_cast_k<<<8192, 256, 0, stream>>>(x, ln1_g, ln1_b, hbuf);
  gemm_bt_k<3><<<64 * 24, 256, 0, stream>>>(hbuf, wqkvT, qkv_b, qkvo, nullptr, nullptr, vT, 8192, 3072, 1024);
  attn_k<<<2048, 256, 0, stream>>>(qkvo, vT, hbuf);
  gemm_bt_k<2><<<64 * 8, 256, 0, stream>>>(hbuf, wprojT, proj_b, nullptr, out, x, nullptr, 8192, 1024, 1024);
  ln_cast_k<<<8192, 256, 0, stream>>>(out, ln2_g, ln2_b, hbuf);
  gemm_bt_k<1><<<64 * 32, 256, 0, stream>>>(hbuf, wfc1T, fc1_b, fc1o, nullptr, nullptr, nullptr, 8192, 4096, 1024);
  gemm_bt_k<2><<<64 * 8, 256, 0, stream>>>(fc1o, wfc2T, fc2_b, nullptr, out, out, nullptr, 8192, 1024, 4096);
}